// Round 1
// baseline (574.049 us; speedup 1.0000x reference)
//
#include <hip/hip_runtime.h>
#include <float.h>

#define NN 20000
#define EE 160000
#define GG 64
#define DD 512
#define NL 3
#define M2 40000
#define M2P 40064   // 313*128
#define M1 20000
#define M1P 20096   // 157*128

typedef __bf16 bf16x8 __attribute__((ext_vector_type(8)));
typedef float f32x4 __attribute__((ext_vector_type(4)));
typedef unsigned int u32;
typedef unsigned short u16;
typedef u32 u32x4 __attribute__((ext_vector_type(4)));
typedef u32 u32x2 __attribute__((ext_vector_type(2)));

union FragU { u32x4 u; bf16x8 b; };

__device__ inline float blo(u32 u){ union{u32 i;float f;}x; x.i=u<<16; return x.f; }
__device__ inline float bhi(u32 u){ union{u32 i;float f;}x; x.i=u&0xFFFF0000u; return x.f; }
__device__ inline float bf2f(u16 v){ union{u32 i;float f;}x; x.i=((u32)v)<<16; return x.f; }
__device__ inline u16 f2bf(float f){ union{float f;u32 i;}x; x.f=f; u32 r=x.i+0x7FFFu+((x.i>>16)&1u); return (u16)(r>>16); }
__device__ inline u32 pack2(float a,float b){ return (u32)f2bf(a) | ((u32)f2bf(b)<<16); }

// ---------------- transpose + fp32->bf16 convert: out[C][R] = in[R][C] ----------------
__global__ void k_transpose_cvt(const float* __restrict__ in, u16* __restrict__ outp, int R, int C){
  __shared__ float t[32][33];
  int c0 = blockIdx.x*32, r0 = blockIdx.y*32;
  t[threadIdx.y][threadIdx.x] = in[(size_t)(r0+threadIdx.y)*C + c0+threadIdx.x];
  __syncthreads();
  outp[(size_t)(c0+threadIdx.y)*R + r0+threadIdx.x] = f2bf(t[threadIdx.x][threadIdx.y]);
}

// ---------------- embed_table @ proj_aa_w + proj_aa_b -> embp[21][512] ----------------
__global__ void k_embp(const float* __restrict__ et, const float* __restrict__ w,
                       const float* __restrict__ b, float* __restrict__ outp){
  int t = blockIdx.x*256+threadIdx.x;
  if(t >= 21*512) return;
  int a = t>>9, d = t&511;
  float s = b[d];
  for(int k=0;k<96;k++) s += et[a*96+k]*w[k*512+d];
  outp[t] = s;
}

// ---------------- degree / dis / scan / csr fill ----------------
__global__ void k_deg(const int* __restrict__ ei, int* __restrict__ deg){
  int e = blockIdx.x*256+threadIdx.x; if(e>=EE) return;
  atomicAdd(&deg[ei[EE+e]], 1);
}
__global__ void k_dis(const int* __restrict__ deg, float* __restrict__ dis){
  int n = blockIdx.x*256+threadIdx.x; if(n>=NN) return;
  dis[n] = rsqrtf((float)deg[n] + 1.0f);
}
__global__ void k_scan(const int* __restrict__ deg, int* __restrict__ offs){
  __shared__ int part[1024];
  int tid = threadIdx.x;
  int base = tid*20;
  int s=0;
  for(int i=0;i<20;i++){ int idx=base+i; if(idx<NN) s += deg[idx]; }
  part[tid]=s; __syncthreads();
  for(int off=1; off<1024; off<<=1){
    int v = (tid>=off)? part[tid-off] : 0;
    __syncthreads();
    part[tid] += v;
    __syncthreads();
  }
  int pre = (tid>0)? part[tid-1] : 0;
  for(int i=0;i<20;i++){ int idx=base+i; if(idx<NN){ offs[idx]=pre; pre += deg[idx]; } }
  if(tid==1023) offs[NN]=part[1023];
}
__global__ void k_fill(const int* __restrict__ ei, const int* __restrict__ offs, int* __restrict__ curs,
                       const float* __restrict__ dis, int* __restrict__ csrs, float* __restrict__ csrw){
  int e = blockIdx.x*256+threadIdx.x; if(e>=EE) return;
  int s = ei[e], d = ei[EE+e];
  int pos = atomicAdd(&curs[d],1);
  int slot = offs[d]+pos;
  csrs[slot]=s;
  csrw[slot]=dis[s]*dis[d];
}

// ---------------- MFMA GEMM: C[M][512] = A[M][K] @ Bt[512][K]^T  (bf16 out) ----------------
// AMODE 0: A is bf16 (padded rows allocated). AMODE 1: A is fp32, guard rows >= Mvalid -> 0.
template<int AMODE>
__global__ __launch_bounds__(256) void k_gemm(const void* __restrict__ Ap, const u16* __restrict__ Bt,
                                              u16* __restrict__ C, int Mvalid, int Mstore, int K, int lda){
  __shared__ u16 lsA[128*40];
  __shared__ u16 lsB[128*40];
  const int tid = threadIdx.x;
  const int lane = tid & 63;
  const int w = tid >> 6;
  const int wr = w >> 1, wc = w & 1;
  const int la = lane & 15, lg = lane >> 4;
  const int n0 = blockIdx.x * 128;
  const int rowB = blockIdx.y * 128;

  f32x4 acc[4][4];
  #pragma unroll
  for(int m=0;m<4;m++)
    #pragma unroll
    for(int n=0;n<4;n++)
      #pragma unroll
      for(int r=0;r<4;r++) acc[m][n][r]=0.f;

  const float* A32 = (const float*)Ap;
  const u16*   A16 = (const u16*)Ap;

  for(int k0=0;k0<K;k0+=32){
    if(AMODE==0){
      #pragma unroll
      for(int i=0;i<2;i++){
        int li=i*256+tid, row=li>>2, seg=li&3;
        u32x4 v = *(const u32x4*)(A16 + (size_t)(rowB+row)*lda + k0 + seg*8);
        *(u32x4*)&lsA[row*40+seg*8] = v;
      }
    } else {
      #pragma unroll
      for(int i=0;i<4;i++){
        int li=i*256+tid, row=li>>3, seg=li&7;
        int gr = rowB+row;
        float4 v = make_float4(0.f,0.f,0.f,0.f);
        if(gr < Mvalid) v = *(const float4*)(A32 + (size_t)gr*lda + k0 + seg*4);
        u32x2 p; p.x = pack2(v.x,v.y); p.y = pack2(v.z,v.w);
        *(u32x2*)&lsA[row*40+seg*4] = p;
      }
    }
    #pragma unroll
    for(int i=0;i<2;i++){
      int li=i*256+tid, row=li>>2, seg=li&3;
      u32x4 v = *(const u32x4*)(Bt + (size_t)(n0+row)*K + k0 + seg*8);
      *(u32x4*)&lsB[row*40+seg*8] = v;
    }
    __syncthreads();
    FragU aF[4], bF[4];
    #pragma unroll
    for(int m=0;m<4;m++) aF[m].u = *(const u32x4*)&lsA[(wr*64+m*16+la)*40 + lg*8];
    #pragma unroll
    for(int n=0;n<4;n++) bF[n].u = *(const u32x4*)&lsB[(wc*64+n*16+la)*40 + lg*8];
    #pragma unroll
    for(int m=0;m<4;m++)
      #pragma unroll
      for(int n=0;n<4;n++)
        acc[m][n] = __builtin_amdgcn_mfma_f32_16x16x32_bf16(aF[m].b, bF[n].b, acc[m][n], 0,0,0);
    __syncthreads();
  }
  #pragma unroll
  for(int m=0;m<4;m++)
    #pragma unroll
    for(int n=0;n<4;n++)
      #pragma unroll
      for(int r=0;r<4;r++){
        int rr = rowB + wr*64 + m*16 + lg*4 + r;
        if(rr < Mstore)
          C[(size_t)rr*512 + n0 + wc*64 + n*16 + la] = f2bf(acc[m][n][r]);
      }
}

// ---------------- fuse: h / x_esm from xW (bf16) ----------------
__global__ void k_fuse(const u16* __restrict__ xW, const int* __restrict__ nx,
                       const float* __restrict__ embp, const float* __restrict__ esm_b,
                       u16* __restrict__ feat){
  int t = blockIdx.x*256+threadIdx.x;
  if(t >= NN*64) return;
  int n = t>>6, c = (t&63)*8;
  uint4 q = *(const uint4*)(xW + (size_t)n*512 + c);
  int a = nx[n];
  float xw[8] = {blo(q.x),bhi(q.x),blo(q.y),bhi(q.y),blo(q.z),bhi(q.z),blo(q.w),bhi(q.w)};
  float h[8], ee[8];
  #pragma unroll
  for(int j=0;j<8;j++){
    float t1 = xw[j] + esm_b[c+j];
    float hh = embp[a*512 + c + j] + t1;
    h[j]  = hh>0.f?hh:0.f;
    ee[j] = t1>0.f?t1:0.f;
  }
  uint4 o1, o2;
  o1.x=pack2(h[0],h[1]); o1.y=pack2(h[2],h[3]); o1.z=pack2(h[4],h[5]); o1.w=pack2(h[6],h[7]);
  o2.x=pack2(ee[0],ee[1]); o2.y=pack2(ee[2],ee[3]); o2.z=pack2(ee[4],ee[5]); o2.w=pack2(ee[6],ee[7]);
  *(uint4*)(feat + (size_t)n*512 + c) = o1;
  *(uint4*)(feat + (size_t)(n+NN)*512 + c) = o2;
}

// ---------------- aggregation + finalize (one wave per dst node, both stacks) ----------------
__global__ __launch_bounds__(64) void k_agg(const u16* __restrict__ hW, u16* __restrict__ feat,
                 const int* __restrict__ offs, const int* __restrict__ csrs,
                 const float* __restrict__ csrw, const float* __restrict__ dis,
                 const float* __restrict__ bias, int layer){
  const int v = blockIdx.x;
  const int lane = threadIdx.x;
  const int nn  = (v < NN) ? v : v - NN;
  const int soff = (v < NN) ? 0 : NN;
  const int e0 = offs[nn], e1 = offs[nn+1];
  float acc[8] = {0,0,0,0,0,0,0,0};
  for(int e=e0;e<e1;++e){
    int s = csrs[e] + soff;
    float wgt = csrw[e];
    uint4 q = *(const uint4*)(hW + (size_t)s*512 + lane*8);
    acc[0]+=wgt*blo(q.x); acc[1]+=wgt*bhi(q.x);
    acc[2]+=wgt*blo(q.y); acc[3]+=wgt*bhi(q.y);
    acc[4]+=wgt*blo(q.z); acc[5]+=wgt*bhi(q.z);
    acc[6]+=wgt*blo(q.w); acc[7]+=wgt*bhi(q.w);
  }
  float dn = dis[nn]; float sn = dn*dn;
  uint4 qs = *(const uint4*)(hW + (size_t)v*512 + lane*8);
  acc[0]+=sn*blo(qs.x); acc[1]+=sn*bhi(qs.x); acc[2]+=sn*blo(qs.y); acc[3]+=sn*bhi(qs.y);
  acc[4]+=sn*blo(qs.z); acc[5]+=sn*bhi(qs.z); acc[6]+=sn*blo(qs.w); acc[7]+=sn*bhi(qs.w);
  float4 b0 = *(const float4*)(bias + lane*8);
  float4 b1 = *(const float4*)(bias + lane*8 + 4);
  acc[0]+=b0.x; acc[1]+=b0.y; acc[2]+=b0.z; acc[3]+=b0.w;
  acc[4]+=b1.x; acc[5]+=b1.y; acc[6]+=b1.z; acc[7]+=b1.w;
  #pragma unroll
  for(int j=0;j<8;j++) acc[j] = acc[j]>0.f ? acc[j] : 0.f;
  if(layer>0){
    uint4 qf = *(const uint4*)(feat + (size_t)v*512 + lane*8);
    acc[0]+=blo(qf.x); acc[1]+=bhi(qf.x); acc[2]+=blo(qf.y); acc[3]+=bhi(qf.y);
    acc[4]+=blo(qf.z); acc[5]+=bhi(qf.z); acc[6]+=blo(qf.w); acc[7]+=bhi(qf.w);
  }
  uint4 o;
  o.x=pack2(acc[0],acc[1]); o.y=pack2(acc[2],acc[3]);
  o.z=pack2(acc[4],acc[5]); o.w=pack2(acc[6],acc[7]);
  *(uint4*)(feat + (size_t)v*512 + lane*8) = o;
}

// ---------------- graph boundaries from sorted batch ----------------
__global__ void k_bounds(const int* __restrict__ batch, int* __restrict__ starts){
  int n = blockIdx.x*256+threadIdx.x;
  if(n>=NN) return;
  int b = batch[n];
  int pb = n ? batch[n-1] : -1;
  for(int g=pb+1; g<=b; g++) starts[g]=n;
  if(n==NN-1){ for(int g=b+1; g<=GG; g++) starts[g]=NN; }
}

// ---------------- partial max pool (values >= 0), atomicMax on float bits ----------------
__global__ void k_pool(const u16* __restrict__ feat, const int* __restrict__ starts,
                       u32* __restrict__ m1, u32* __restrict__ m3){
  int g = blockIdx.x, c = blockIdx.y;
  int s = starts[g], e = starts[g+1];
  int len = e - s;
  int b0 = s + (len*c)/8, b1 = s + (len*(c+1))/8;
  int t = threadIdx.x;
  float a0=0.f, a1=0.f, c0=0.f, c1=0.f;
  for(int n=b0;n<b1;++n){
    const u16* r1p = feat + (size_t)n*512;
    const u16* r3p = feat + (size_t)(n+NN)*512;
    a0 = fmaxf(a0, bf2f(r1p[t]));
    a1 = fmaxf(a1, bf2f(r1p[t+256]));
    c0 = fmaxf(c0, bf2f(r3p[t]));
    c1 = fmaxf(c1, bf2f(r3p[t+256]));
  }
  atomicMax(m1 + g*512 + t,       __float_as_uint(a0));
  atomicMax(m1 + g*512 + t + 256, __float_as_uint(a1));
  atomicMax(m3 + g*512 + t,       __float_as_uint(c0));
  atomicMax(m3 + g*512 + t + 256, __float_as_uint(c1));
}
__global__ void k_gcomb(const u32* __restrict__ m1, const u32* __restrict__ m3,
                        const float* __restrict__ w1, float* __restrict__ gc){
  int t = blockIdx.x*256+threadIdx.x; if(t>=GG*512) return;
  gc[t] = w1[0]*__uint_as_float(m1[t]) + w1[1]*__uint_as_float(m3[t]);
}

// ---------------- readout ----------------
__global__ void k_ro1(const float* __restrict__ gc, const float* __restrict__ w,
                      const float* __restrict__ b, float* __restrict__ r1){
  int t = blockIdx.x*256+threadIdx.x; if(t>=GG*1024) return;
  int g = t>>10, o = t&1023;
  float s = b[o];
  for(int k=0;k<512;k++) s += gc[g*512+k]*w[k*1024+o];
  r1[t] = s>0.f ? s : 0.f;
}
__global__ void k_ro2(const float* __restrict__ r1, const float* __restrict__ w,
                      const float* __restrict__ b, float* __restrict__ y){
  int t = blockIdx.x*256+threadIdx.x; if(t>=GG*500) return;
  int g = t/500, o = t%500;
  float s = b[o];
  for(int k=0;k<1024;k++) s += r1[g*1024+k]*w[k*500+o];
  y[t] = 1.0f/(1.0f+__expf(-s));
}

extern "C" void kernel_launch(void* const* d_in, const int* in_sizes, int n_in,
                              void* d_out, int out_size, void* d_ws, size_t ws_size,
                              hipStream_t stream){
  const int*   native_x = (const int*)d_in[0];
  const float* x        = (const float*)d_in[1];
  const int*   ei       = (const int*)d_in[2];
  const int*   batch    = (const int*)d_in[3];
  const float* embed_t  = (const float*)d_in[4];
  const float* paa_w    = (const float*)d_in[5];
  const float* paa_b    = (const float*)d_in[6];
  const float* pesm_w   = (const float*)d_in[7];
  const float* pesm_b   = (const float*)d_in[8];
  const float* gcn_w    = (const float*)d_in[9];
  const float* gcn_b    = (const float*)d_in[10];
  const float* ro1_w    = (const float*)d_in[11];
  const float* ro1_b    = (const float*)d_in[12];
  const float* ro2_w    = (const float*)d_in[13];
  const float* ro2_b    = (const float*)d_in[14];
  const float* w1       = (const float*)d_in[15];
  float* out = (float*)d_out;

  char* p = (char*)d_ws;
  auto alloc = [&](size_t n){ void* r = (void*)p; p += (n + 255) & ~(size_t)255; return r; };
  u16* feat   = (u16*)alloc((size_t)M2P*512*2);
  u16* hW     = (u16*)alloc((size_t)M2P*512*2);
  u16* WtE    = (u16*)alloc((size_t)512*1280*2);
  u16* WtG    = (u16*)alloc((size_t)3*512*512*2);
  float* embp = (float*)alloc(21*512*4);
  int* deg    = (int*)alloc(NN*4);
  float* dis  = (float*)alloc(NN*4);
  int* offs   = (int*)alloc((NN+1)*4);
  int* curs   = (int*)alloc(NN*4);
  int* csrs   = (int*)alloc(EE*4);
  float* csrw = (float*)alloc(EE*4);
  int* starts = (int*)alloc((GG+1)*4);
  u32* m1b    = (u32*)alloc(GG*512*4);
  u32* m3b    = (u32*)alloc(GG*512*4);
  float* gc   = (float*)alloc(GG*512*4);
  float* r1   = (float*)alloc(GG*1024*4);
  (void)ws_size; (void)in_sizes; (void)n_in; (void)out_size;

  hipMemsetAsync(deg,  0, NN*4, stream);
  hipMemsetAsync(curs, 0, NN*4, stream);
  hipMemsetAsync(m1b,  0, GG*512*4, stream);
  hipMemsetAsync(m3b,  0, GG*512*4, stream);

  k_transpose_cvt<<<dim3(16,40),dim3(32,32),0,stream>>>(pesm_w, WtE, 1280, 512);
  for(int i=0;i<3;i++)
    k_transpose_cvt<<<dim3(16,16),dim3(32,32),0,stream>>>(gcn_w+(size_t)i*262144, WtG+(size_t)i*262144, 512, 512);
  k_embp<<<42,256,0,stream>>>(embed_t, paa_w, paa_b, embp);
  k_deg<<<(EE+255)/256,256,0,stream>>>(ei, deg);
  k_dis<<<(NN+255)/256,256,0,stream>>>(deg, dis);
  k_scan<<<1,1024,0,stream>>>(deg, offs);
  k_fill<<<(EE+255)/256,256,0,stream>>>(ei, offs, curs, dis, csrs, csrw);

  // x @ proj_esm_w  (fp32 A converted in staging) -> hW (bf16, rows 0..20000)
  k_gemm<1><<<dim3(4,157),256,0,stream>>>((const void*)x, WtE, hW, M1, M1, 1280, 1280);
  k_fuse<<<(NN*64+255)/256,256,0,stream>>>(hW, native_x, embp, pesm_b, feat);

  for(int i=0;i<3;i++){
    k_gemm<0><<<dim3(4,313),256,0,stream>>>((const void*)feat, WtG+(size_t)i*262144, hW, M2P, M2, 512, 512);
    k_agg<<<M2,64,0,stream>>>(hW, feat, offs, csrs, csrw, dis, gcn_b+(size_t)i*512, i);
  }

  k_bounds<<<(NN+255)/256,256,0,stream>>>(batch, starts);
  k_pool<<<dim3(GG,8),256,0,stream>>>(feat, starts, m1b, m3b);
  k_gcomb<<<(GG*512+255)/256,256,0,stream>>>(m1b, m3b, w1, gc);
  k_ro1<<<(GG*1024+255)/256,256,0,stream>>>(gc, ro1_w, ro1_b, r1);
  k_ro2<<<(GG*500+255)/256,256,0,stream>>>(r1, ro2_w, ro2_b, out);
}

// Round 2
// 528.773 us; speedup vs baseline: 1.0856x; 1.0856x over previous
//
#include <hip/hip_runtime.h>
#include <float.h>

#define NN 20000
#define EE 160000
#define GG 64
#define DD 512
#define NL 3
#define M2 40000
#define M2P 40064   // 313*128
#define M1 20000
#define M1P 20096   // 157*128
#define BK 64

typedef __bf16 bf16x8 __attribute__((ext_vector_type(8)));
typedef float f32x4 __attribute__((ext_vector_type(4)));
typedef unsigned int u32;
typedef unsigned short u16;
typedef u32 u32x4 __attribute__((ext_vector_type(4)));
typedef u32 u32x2 __attribute__((ext_vector_type(2)));

union FragU { u32x4 u; bf16x8 b; };

__device__ inline float blo(u32 u){ union{u32 i;float f;}x; x.i=u<<16; return x.f; }
__device__ inline float bhi(u32 u){ union{u32 i;float f;}x; x.i=u&0xFFFF0000u; return x.f; }
__device__ inline float bf2f(u16 v){ union{u32 i;float f;}x; x.i=((u32)v)<<16; return x.f; }
__device__ inline u16 f2bf(float f){ union{float f;u32 i;}x; x.f=f; u32 r=x.i+0x7FFFu+((x.i>>16)&1u); return (u16)(r>>16); }
__device__ inline u32 pack2(float a,float b){ return (u32)f2bf(a) | ((u32)f2bf(b)<<16); }

__device__ __forceinline__ void gload16(const void* g, void* lds){
  __builtin_amdgcn_global_load_lds(
    (const __attribute__((address_space(1))) void*)g,
    (__attribute__((address_space(3))) void*)lds, 16, 0, 0);
}

// ---------------- fp32 -> bf16 convert with row padding (pad rows = 0) ----------------
__global__ void k_cvt(const float* __restrict__ in, u16* __restrict__ outp){
  int t = blockIdx.x*256+threadIdx.x;
  if(t >= M1P*160) return;            // 160 groups of 8 per 1280-row
  int row = t/160, gidx = t%160;
  u32x4 o;
  if(row < M1){
    const float* s = in + (size_t)row*1280 + gidx*8;
    float4 v0 = *(const float4*)s;
    float4 v1 = *(const float4*)(s+4);
    o.x=pack2(v0.x,v0.y); o.y=pack2(v0.z,v0.w);
    o.z=pack2(v1.x,v1.y); o.w=pack2(v1.z,v1.w);
  } else {
    o.x=o.y=o.z=o.w=0u;
  }
  *(u32x4*)(outp + (size_t)row*1280 + gidx*8) = o;
}

// ---------------- transpose + fp32->bf16 convert: out[C][R] = in[R][C] ----------------
__global__ void k_transpose_cvt(const float* __restrict__ in, u16* __restrict__ outp, int R, int C){
  __shared__ float t[32][33];
  int c0 = blockIdx.x*32, r0 = blockIdx.y*32;
  t[threadIdx.y][threadIdx.x] = in[(size_t)(r0+threadIdx.y)*C + c0+threadIdx.x];
  __syncthreads();
  outp[(size_t)(c0+threadIdx.y)*R + r0+threadIdx.x] = f2bf(t[threadIdx.x][threadIdx.y]);
}

// ---------------- embed_table @ proj_aa_w + proj_aa_b -> embp[21][512] ----------------
__global__ void k_embp(const float* __restrict__ et, const float* __restrict__ w,
                       const float* __restrict__ b, float* __restrict__ outp){
  int t = blockIdx.x*256+threadIdx.x;
  if(t >= 21*512) return;
  int a = t>>9, d = t&511;
  float s = b[d];
  for(int k=0;k<96;k++) s += et[a*96+k]*w[k*512+d];
  outp[t] = s;
}

// ---------------- degree / dis / scan / csr fill ----------------
__global__ void k_deg(const int* __restrict__ ei, int* __restrict__ deg){
  int e = blockIdx.x*256+threadIdx.x; if(e>=EE) return;
  atomicAdd(&deg[ei[EE+e]], 1);
}
__global__ void k_dis(const int* __restrict__ deg, float* __restrict__ dis){
  int n = blockIdx.x*256+threadIdx.x; if(n>=NN) return;
  dis[n] = rsqrtf((float)deg[n] + 1.0f);
}
__global__ void k_scan(const int* __restrict__ deg, int* __restrict__ offs){
  __shared__ int part[1024];
  int tid = threadIdx.x;
  int base = tid*20;
  int s=0;
  for(int i=0;i<20;i++){ int idx=base+i; if(idx<NN) s += deg[idx]; }
  part[tid]=s; __syncthreads();
  for(int off=1; off<1024; off<<=1){
    int v = (tid>=off)? part[tid-off] : 0;
    __syncthreads();
    part[tid] += v;
    __syncthreads();
  }
  int pre = (tid>0)? part[tid-1] : 0;
  for(int i=0;i<20;i++){ int idx=base+i; if(idx<NN){ offs[idx]=pre; pre += deg[idx]; } }
  if(tid==1023) offs[NN]=part[1023];
}
__global__ void k_fill(const int* __restrict__ ei, const int* __restrict__ offs, int* __restrict__ curs,
                       const float* __restrict__ dis, int* __restrict__ csrs, float* __restrict__ csrw){
  int e = blockIdx.x*256+threadIdx.x; if(e>=EE) return;
  int s = ei[e], d = ei[EE+e];
  int pos = atomicAdd(&curs[d],1);
  int slot = offs[d]+pos;
  csrs[slot]=s;
  csrw[slot]=dis[s]*dis[d];
}

// ---------------- MFMA GEMM (m97 structure): C[M][512] = A[M][K] @ Bt[512][K]^T ----------------
// A bf16 padded rows; global_load_lds width-16 staging; XOR-chunk swizzled LDS (BK=64).
__global__ __launch_bounds__(256) void k_gemm(const u16* __restrict__ A, const u16* __restrict__ Bt,
                                              u16* __restrict__ C, int Mstore, int K, int lda){
  __shared__ u16 lsA[128*BK];
  __shared__ u16 lsB[128*BK];
  const int tid = threadIdx.x;
  const int lane = tid & 63;
  const int wid = tid >> 6;
  const int wr = wid >> 1, wc = wid & 1;
  const int la = lane & 15, lg = lane >> 4;
  const int n0 = blockIdx.x * 128;
  const int rowB = blockIdx.y * 128;

  f32x4 acc[4][4];
  #pragma unroll
  for(int m=0;m<4;m++)
    #pragma unroll
    for(int n=0;n<4;n++)
      #pragma unroll
      for(int r=0;r<4;r++) acc[m][n][r]=0.f;

  const u16* Arow = A + (size_t)rowB*lda;
  const u16* Brow = Bt + (size_t)n0*K;

  // per-thread staging decode: chunk li = i*256+tid; row=li>>3, cir=li&7; src chunk = cir^(row&7)
  int srow[4], scol[4], ldsoff[4];
  #pragma unroll
  for(int i=0;i<4;i++){
    int li = i*256+tid;
    srow[i] = li>>3;
    scol[i] = ((li&7) ^ (srow[i]&7))*8;
    ldsoff[i] = (i*256 + wid*64)*8;     // wave-uniform u16 offset
  }

  for(int k0=0;k0<K;k0+=BK){
    #pragma unroll
    for(int i=0;i<4;i++)
      gload16(Arow + (size_t)srow[i]*lda + k0 + scol[i], lsA + ldsoff[i]);
    #pragma unroll
    for(int i=0;i<4;i++)
      gload16(Brow + (size_t)srow[i]*K + k0 + scol[i], lsB + ldsoff[i]);
    __syncthreads();
    #pragma unroll
    for(int kk=0;kk<2;kk++){
      FragU aF[4], bF[4];
      #pragma unroll
      for(int m=0;m<4;m++){
        int row = wr*64+m*16+la;
        aF[m].u = *(const u32x4*)&lsA[row*BK + ((kk*4+lg)^(row&7))*8];
      }
      #pragma unroll
      for(int n=0;n<4;n++){
        int row = wc*64+n*16+la;
        bF[n].u = *(const u32x4*)&lsB[row*BK + ((kk*4+lg)^(row&7))*8];
      }
      #pragma unroll
      for(int m=0;m<4;m++)
        #pragma unroll
        for(int n=0;n<4;n++)
          acc[m][n] = __builtin_amdgcn_mfma_f32_16x16x32_bf16(aF[m].b, bF[n].b, acc[m][n], 0,0,0);
    }
    __syncthreads();
  }
  #pragma unroll
  for(int m=0;m<4;m++)
    #pragma unroll
    for(int n=0;n<4;n++)
      #pragma unroll
      for(int r=0;r<4;r++){
        int rr = rowB + wr*64 + m*16 + lg*4 + r;
        if(rr < Mstore)
          C[(size_t)rr*512 + n0 + wc*64 + n*16 + la] = f2bf(acc[m][n][r]);
      }
}

// ---------------- fuse: h / x_esm from xW (bf16) ----------------
__global__ void k_fuse(const u16* __restrict__ xW, const int* __restrict__ nx,
                       const float* __restrict__ embp, const float* __restrict__ esm_b,
                       u16* __restrict__ feat){
  int t = blockIdx.x*256+threadIdx.x;
  if(t >= NN*64) return;
  int n = t>>6, c = (t&63)*8;
  uint4 q = *(const uint4*)(xW + (size_t)n*512 + c);
  int a = nx[n];
  float xw[8] = {blo(q.x),bhi(q.x),blo(q.y),bhi(q.y),blo(q.z),bhi(q.z),blo(q.w),bhi(q.w)};
  float h[8], ee[8];
  #pragma unroll
  for(int j=0;j<8;j++){
    float t1 = xw[j] + esm_b[c+j];
    float hh = embp[a*512 + c + j] + t1;
    h[j]  = hh>0.f?hh:0.f;
    ee[j] = t1>0.f?t1:0.f;
  }
  uint4 o1, o2;
  o1.x=pack2(h[0],h[1]); o1.y=pack2(h[2],h[3]); o1.z=pack2(h[4],h[5]); o1.w=pack2(h[6],h[7]);
  o2.x=pack2(ee[0],ee[1]); o2.y=pack2(ee[2],ee[3]); o2.z=pack2(ee[4],ee[5]); o2.w=pack2(ee[6],ee[7]);
  *(uint4*)(feat + (size_t)n*512 + c) = o1;
  *(uint4*)(feat + (size_t)(n+NN)*512 + c) = o2;
}

// ---------------- aggregation + finalize (one wave per dst node, both stacks) ----------------
__global__ __launch_bounds__(64) void k_agg(const u16* __restrict__ hW, u16* __restrict__ feat,
                 const int* __restrict__ offs, const int* __restrict__ csrs,
                 const float* __restrict__ csrw, const float* __restrict__ dis,
                 const float* __restrict__ bias, int layer){
  const int v = blockIdx.x;
  const int lane = threadIdx.x;
  const int nn  = (v < NN) ? v : v - NN;
  const int soff = (v < NN) ? 0 : NN;
  const int e0 = offs[nn], e1 = offs[nn+1];
  float acc[8] = {0,0,0,0,0,0,0,0};
  for(int e=e0;e<e1;++e){
    int s = csrs[e] + soff;
    float wgt = csrw[e];
    uint4 q = *(const uint4*)(hW + (size_t)s*512 + lane*8);
    acc[0]+=wgt*blo(q.x); acc[1]+=wgt*bhi(q.x);
    acc[2]+=wgt*blo(q.y); acc[3]+=wgt*bhi(q.y);
    acc[4]+=wgt*blo(q.z); acc[5]+=wgt*bhi(q.z);
    acc[6]+=wgt*blo(q.w); acc[7]+=wgt*bhi(q.w);
  }
  float dn = dis[nn]; float sn = dn*dn;
  uint4 qs = *(const uint4*)(hW + (size_t)v*512 + lane*8);
  acc[0]+=sn*blo(qs.x); acc[1]+=sn*bhi(qs.x); acc[2]+=sn*blo(qs.y); acc[3]+=sn*bhi(qs.y);
  acc[4]+=sn*blo(qs.z); acc[5]+=sn*bhi(qs.z); acc[6]+=sn*blo(qs.w); acc[7]+=sn*bhi(qs.w);
  float4 b0 = *(const float4*)(bias + lane*8);
  float4 b1 = *(const float4*)(bias + lane*8 + 4);
  acc[0]+=b0.x; acc[1]+=b0.y; acc[2]+=b0.z; acc[3]+=b0.w;
  acc[4]+=b1.x; acc[5]+=b1.y; acc[6]+=b1.z; acc[7]+=b1.w;
  #pragma unroll
  for(int j=0;j<8;j++) acc[j] = acc[j]>0.f ? acc[j] : 0.f;
  if(layer>0){
    uint4 qf = *(const uint4*)(feat + (size_t)v*512 + lane*8);
    acc[0]+=blo(qf.x); acc[1]+=bhi(qf.x); acc[2]+=blo(qf.y); acc[3]+=bhi(qf.y);
    acc[4]+=blo(qf.z); acc[5]+=bhi(qf.z); acc[6]+=blo(qf.w); acc[7]+=bhi(qf.w);
  }
  uint4 o;
  o.x=pack2(acc[0],acc[1]); o.y=pack2(acc[2],acc[3]);
  o.z=pack2(acc[4],acc[5]); o.w=pack2(acc[6],acc[7]);
  *(uint4*)(feat + (size_t)v*512 + lane*8) = o;
}

// ---------------- graph boundaries from sorted batch ----------------
__global__ void k_bounds(const int* __restrict__ batch, int* __restrict__ starts){
  int n = blockIdx.x*256+threadIdx.x;
  if(n>=NN) return;
  int b = batch[n];
  int pb = n ? batch[n-1] : -1;
  for(int g=pb+1; g<=b; g++) starts[g]=n;
  if(n==NN-1){ for(int g=b+1; g<=GG; g++) starts[g]=NN; }
}

// ---------------- partial max pool (values >= 0), atomicMax on float bits ----------------
__global__ void k_pool(const u16* __restrict__ feat, const int* __restrict__ starts,
                       u32* __restrict__ m1, u32* __restrict__ m3){
  int g = blockIdx.x, c = blockIdx.y;
  int s = starts[g], e = starts[g+1];
  int len = e - s;
  int b0 = s + (len*c)/8, b1 = s + (len*(c+1))/8;
  int t = threadIdx.x;
  float a0=0.f, a1=0.f, c0=0.f, c1=0.f;
  for(int n=b0;n<b1;++n){
    const u16* r1p = feat + (size_t)n*512;
    const u16* r3p = feat + (size_t)(n+NN)*512;
    a0 = fmaxf(a0, bf2f(r1p[t]));
    a1 = fmaxf(a1, bf2f(r1p[t+256]));
    c0 = fmaxf(c0, bf2f(r3p[t]));
    c1 = fmaxf(c1, bf2f(r3p[t+256]));
  }
  atomicMax(m1 + g*512 + t,       __float_as_uint(a0));
  atomicMax(m1 + g*512 + t + 256, __float_as_uint(a1));
  atomicMax(m3 + g*512 + t,       __float_as_uint(c0));
  atomicMax(m3 + g*512 + t + 256, __float_as_uint(c1));
}
__global__ void k_gcomb(const u32* __restrict__ m1, const u32* __restrict__ m3,
                        const float* __restrict__ w1, float* __restrict__ gc){
  int t = blockIdx.x*256+threadIdx.x; if(t>=GG*512) return;
  gc[t] = w1[0]*__uint_as_float(m1[t]) + w1[1]*__uint_as_float(m3[t]);
}

// ---------------- readout ----------------
__global__ void k_ro1(const float* __restrict__ gc, const float* __restrict__ w,
                      const float* __restrict__ b, float* __restrict__ r1){
  int t = blockIdx.x*256+threadIdx.x; if(t>=GG*1024) return;
  int g = t>>10, o = t&1023;
  float s = b[o];
  for(int k=0;k<512;k++) s += gc[g*512+k]*w[k*1024+o];
  r1[t] = s>0.f ? s : 0.f;
}
__global__ void k_ro2(const float* __restrict__ r1, const float* __restrict__ w,
                      const float* __restrict__ b, float* __restrict__ y){
  int t = blockIdx.x*256+threadIdx.x; if(t>=GG*500) return;
  int g = t/500, o = t%500;
  float s = b[o];
  for(int k=0;k<1024;k++) s += r1[g*1024+k]*w[k*500+o];
  y[t] = 1.0f/(1.0f+__expf(-s));
}

extern "C" void kernel_launch(void* const* d_in, const int* in_sizes, int n_in,
                              void* d_out, int out_size, void* d_ws, size_t ws_size,
                              hipStream_t stream){
  const int*   native_x = (const int*)d_in[0];
  const float* x        = (const float*)d_in[1];
  const int*   ei       = (const int*)d_in[2];
  const int*   batch    = (const int*)d_in[3];
  const float* embed_t  = (const float*)d_in[4];
  const float* paa_w    = (const float*)d_in[5];
  const float* paa_b    = (const float*)d_in[6];
  const float* pesm_w   = (const float*)d_in[7];
  const float* pesm_b   = (const float*)d_in[8];
  const float* gcn_w    = (const float*)d_in[9];
  const float* gcn_b    = (const float*)d_in[10];
  const float* ro1_w    = (const float*)d_in[11];
  const float* ro1_b    = (const float*)d_in[12];
  const float* ro2_w    = (const float*)d_in[13];
  const float* ro2_b    = (const float*)d_in[14];
  const float* w1       = (const float*)d_in[15];
  float* out = (float*)d_out;

  char* p = (char*)d_ws;
  auto alloc = [&](size_t n){ void* r = (void*)p; p += (n + 255) & ~(size_t)255; return r; };
  u16* feat   = (u16*)alloc((size_t)M2P*512*2);
  u16* hW     = (u16*)alloc((size_t)M2P*512*2);
  u16* xbf    = (u16*)alloc((size_t)M1P*1280*2);
  u16* WtE    = (u16*)alloc((size_t)512*1280*2);
  u16* WtG    = (u16*)alloc((size_t)3*512*512*2);
  float* embp = (float*)alloc(21*512*4);
  int* deg    = (int*)alloc(NN*4);
  float* dis  = (float*)alloc(NN*4);
  int* offs   = (int*)alloc((NN+1)*4);
  int* curs   = (int*)alloc(NN*4);
  int* csrs   = (int*)alloc(EE*4);
  float* csrw = (float*)alloc(EE*4);
  int* starts = (int*)alloc((GG+1)*4);
  u32* m1b    = (u32*)alloc(GG*512*4);
  u32* m3b    = (u32*)alloc(GG*512*4);
  float* gc   = (float*)alloc(GG*512*4);
  float* r1   = (float*)alloc(GG*1024*4);
  (void)ws_size; (void)in_sizes; (void)n_in; (void)out_size;

  hipMemsetAsync(deg,  0, NN*4, stream);
  hipMemsetAsync(curs, 0, NN*4, stream);
  hipMemsetAsync(m1b,  0, GG*512*4, stream);
  hipMemsetAsync(m3b,  0, GG*512*4, stream);

  k_cvt<<<(M1P*160+255)/256,256,0,stream>>>(x, xbf);
  k_transpose_cvt<<<dim3(16,40),dim3(32,32),0,stream>>>(pesm_w, WtE, 1280, 512);
  for(int i=0;i<3;i++)
    k_transpose_cvt<<<dim3(16,16),dim3(32,32),0,stream>>>(gcn_w+(size_t)i*262144, WtG+(size_t)i*262144, 512, 512);
  k_embp<<<42,256,0,stream>>>(embed_t, paa_w, paa_b, embp);
  k_deg<<<(EE+255)/256,256,0,stream>>>(ei, deg);
  k_dis<<<(NN+255)/256,256,0,stream>>>(deg, dis);
  k_scan<<<1,1024,0,stream>>>(deg, offs);
  k_fill<<<(EE+255)/256,256,0,stream>>>(ei, offs, curs, dis, csrs, csrw);

  // x @ proj_esm_w -> hW (bf16, rows stored 0..20000)
  k_gemm<<<dim3(4,157),256,0,stream>>>(xbf, WtE, hW, M1, 1280, 1280);
  k_fuse<<<(NN*64+255)/256,256,0,stream>>>(hW, native_x, embp, pesm_b, feat);

  for(int i=0;i<3;i++){
    k_gemm<<<dim3(4,313),256,0,stream>>>(feat, WtG+(size_t)i*262144, hW, M2, 512, 512);
    k_agg<<<M2,64,0,stream>>>(hW, feat, offs, csrs, csrw, dis, gcn_b+(size_t)i*512, i);
  }

  k_bounds<<<(NN+255)/256,256,0,stream>>>(batch, starts);
  k_pool<<<dim3(GG,8),256,0,stream>>>(feat, starts, m1b, m3b);
  k_gcomb<<<(GG*512+255)/256,256,0,stream>>>(m1b, m3b, w1, gc);
  k_ro1<<<(GG*1024+255)/256,256,0,stream>>>(gc, ro1_w, ro1_b, r1);
  k_ro2<<<(GG*500+255)/256,256,0,stream>>>(r1, ro2_w, ro2_b, out);
}

// Round 3
// 481.667 us; speedup vs baseline: 1.1918x; 1.0978x over previous
//
#include <hip/hip_runtime.h>
#include <float.h>

#define NN 20000
#define EE 160000
#define GG 64
#define DD 512
#define NL 3
#define M2 40000
#define M2P 40064   // 313*128
#define M1 20000
#define M1P 20096   // 157*128
#define BK 64

typedef __bf16 bf16x8 __attribute__((ext_vector_type(8)));
typedef float f32x4 __attribute__((ext_vector_type(4)));
typedef unsigned int u32;
typedef unsigned short u16;
typedef u32 u32x4 __attribute__((ext_vector_type(4)));
typedef u32 u32x2 __attribute__((ext_vector_type(2)));

union FragU { u32x4 u; bf16x8 b; };

__device__ inline float blo(u32 u){ union{u32 i;float f;}x; x.i=u<<16; return x.f; }
__device__ inline float bhi(u32 u){ union{u32 i;float f;}x; x.i=u&0xFFFF0000u; return x.f; }
__device__ inline float bf2f(u16 v){ union{u32 i;float f;}x; x.i=((u32)v)<<16; return x.f; }
__device__ inline u16 f2bf(float f){ union{float f;u32 i;}x; x.f=f; u32 r=x.i+0x7FFFu+((x.i>>16)&1u); return (u16)(r>>16); }
__device__ inline u32 pack2(float a,float b){ return (u32)f2bf(a) | ((u32)f2bf(b)<<16); }

__device__ __forceinline__ void gload16(const void* g, void* lds){
  __builtin_amdgcn_global_load_lds(
    (const __attribute__((address_space(1))) void*)g,
    (__attribute__((address_space(3))) void*)lds, 16, 0, 0);
}

// ---------------- fp32 -> bf16 convert with row padding (pad rows = 0) ----------------
__global__ void k_cvt(const float* __restrict__ in, u16* __restrict__ outp){
  int t = blockIdx.x*256+threadIdx.x;
  if(t >= M1P*160) return;            // 160 groups of 8 per 1280-row
  int row = t/160, gidx = t%160;
  u32x4 o;
  if(row < M1){
    const float* s = in + (size_t)row*1280 + gidx*8;
    float4 v0 = *(const float4*)s;
    float4 v1 = *(const float4*)(s+4);
    o.x=pack2(v0.x,v0.y); o.y=pack2(v0.z,v0.w);
    o.z=pack2(v1.x,v1.y); o.w=pack2(v1.z,v1.w);
  } else {
    o.x=o.y=o.z=o.w=0u;
  }
  *(u32x4*)(outp + (size_t)row*1280 + gidx*8) = o;
}

// ---------------- transpose + fp32->bf16 convert: out[C][R] = in[R][C] ----------------
__global__ void k_transpose_cvt(const float* __restrict__ in, u16* __restrict__ outp, int R, int C){
  __shared__ float t[32][33];
  int c0 = blockIdx.x*32, r0 = blockIdx.y*32;
  t[threadIdx.y][threadIdx.x] = in[(size_t)(r0+threadIdx.y)*C + c0+threadIdx.x];
  __syncthreads();
  outp[(size_t)(c0+threadIdx.y)*R + r0+threadIdx.x] = f2bf(t[threadIdx.x][threadIdx.y]);
}

// ---------------- fp32 transpose with bounds: out[C][R] = in[R][C] ----------------
__global__ void k_transpose_f32(const float* __restrict__ in, float* __restrict__ outp, int R, int C){
  __shared__ float t[32][33];
  int c0 = blockIdx.x*32, r0 = blockIdx.y*32;
  int r = r0+threadIdx.y, c = c0+threadIdx.x;
  if(r<R && c<C) t[threadIdx.y][threadIdx.x] = in[(size_t)r*C + c];
  __syncthreads();
  int oc = c0+threadIdx.y, orr = r0+threadIdx.x;
  if(oc<C && orr<R) outp[(size_t)oc*R + orr] = t[threadIdx.x][threadIdx.y];
}

// ---------------- embed_table @ proj_aa_w + proj_aa_b -> embp[21][512] ----------------
__global__ void k_embp(const float* __restrict__ et, const float* __restrict__ w,
                       const float* __restrict__ b, float* __restrict__ outp){
  int t = blockIdx.x*256+threadIdx.x;
  if(t >= 21*512) return;
  int a = t>>9, d = t&511;
  float s = b[d];
  for(int k=0;k<96;k++) s += et[a*96+k]*w[k*512+d];
  outp[t] = s;
}

// ---------------- degree / dis / scan / csr fill ----------------
__global__ void k_deg(const int* __restrict__ ei, int* __restrict__ deg){
  int e = blockIdx.x*256+threadIdx.x; if(e>=EE) return;
  atomicAdd(&deg[ei[EE+e]], 1);
}
__global__ void k_dis(const int* __restrict__ deg, float* __restrict__ dis){
  int n = blockIdx.x*256+threadIdx.x; if(n>=NN) return;
  dis[n] = rsqrtf((float)deg[n] + 1.0f);
}
__global__ void k_scan(const int* __restrict__ deg, int* __restrict__ offs){
  __shared__ int part[1024];
  int tid = threadIdx.x;
  int base = tid*20;
  int s=0;
  for(int i=0;i<20;i++){ int idx=base+i; if(idx<NN) s += deg[idx]; }
  part[tid]=s; __syncthreads();
  for(int off=1; off<1024; off<<=1){
    int v = (tid>=off)? part[tid-off] : 0;
    __syncthreads();
    part[tid] += v;
    __syncthreads();
  }
  int pre = (tid>0)? part[tid-1] : 0;
  for(int i=0;i<20;i++){ int idx=base+i; if(idx<NN){ offs[idx]=pre; pre += deg[idx]; } }
  if(tid==1023) offs[NN]=part[1023];
}
__global__ void k_fill(const int* __restrict__ ei, const int* __restrict__ offs, int* __restrict__ curs,
                       const float* __restrict__ dis, int* __restrict__ csrs, float* __restrict__ csrw){
  int e = blockIdx.x*256+threadIdx.x; if(e>=EE) return;
  int s = ei[e], d = ei[EE+e];
  int pos = atomicAdd(&curs[d],1);
  int slot = offs[d]+pos;
  csrs[slot]=s;
  csrw[slot]=dis[s]*dis[d];
}

// ---------------- MFMA GEMM (m97 structure): C[M][512] = A[M][K] @ Bt[512][K]^T ----------------
__global__ __launch_bounds__(256) void k_gemm(const u16* __restrict__ A, const u16* __restrict__ Bt,
                                              u16* __restrict__ C, int Mstore, int K, int lda){
  __shared__ u16 lsA[128*BK];
  __shared__ u16 lsB[128*BK];
  const int tid = threadIdx.x;
  const int lane = tid & 63;
  const int wid = tid >> 6;
  const int wr = wid >> 1, wc = wid & 1;
  const int la = lane & 15, lg = lane >> 4;
  const int n0 = blockIdx.x * 128;
  const int rowB = blockIdx.y * 128;

  f32x4 acc[4][4];
  #pragma unroll
  for(int m=0;m<4;m++)
    #pragma unroll
    for(int n=0;n<4;n++)
      #pragma unroll
      for(int r=0;r<4;r++) acc[m][n][r]=0.f;

  const u16* Arow = A + (size_t)rowB*lda;
  const u16* Brow = Bt + (size_t)n0*K;

  int srow[4], scol[4], ldsoff[4];
  #pragma unroll
  for(int i=0;i<4;i++){
    int li = i*256+tid;
    srow[i] = li>>3;
    scol[i] = ((li&7) ^ (srow[i]&7))*8;
    ldsoff[i] = (i*256 + wid*64)*8;     // wave-uniform u16 offset
  }

  for(int k0=0;k0<K;k0+=BK){
    #pragma unroll
    for(int i=0;i<4;i++)
      gload16(Arow + (size_t)srow[i]*lda + k0 + scol[i], lsA + ldsoff[i]);
    #pragma unroll
    for(int i=0;i<4;i++)
      gload16(Brow + (size_t)srow[i]*K + k0 + scol[i], lsB + ldsoff[i]);
    __syncthreads();
    #pragma unroll
    for(int kk=0;kk<2;kk++){
      FragU aF[4], bF[4];
      #pragma unroll
      for(int m=0;m<4;m++){
        int row = wr*64+m*16+la;
        aF[m].u = *(const u32x4*)&lsA[row*BK + ((kk*4+lg)^(row&7))*8];
      }
      #pragma unroll
      for(int n=0;n<4;n++){
        int row = wc*64+n*16+la;
        bF[n].u = *(const u32x4*)&lsB[row*BK + ((kk*4+lg)^(row&7))*8];
      }
      #pragma unroll
      for(int m=0;m<4;m++)
        #pragma unroll
        for(int n=0;n<4;n++)
          acc[m][n] = __builtin_amdgcn_mfma_f32_16x16x32_bf16(aF[m].b, bF[n].b, acc[m][n], 0,0,0);
    }
    __syncthreads();
  }
  #pragma unroll
  for(int m=0;m<4;m++)
    #pragma unroll
    for(int n=0;n<4;n++)
      #pragma unroll
      for(int r=0;r<4;r++){
        int rr = rowB + wr*64 + m*16 + lg*4 + r;
        if(rr < Mstore)
          C[(size_t)rr*512 + n0 + wc*64 + n*16 + la] = f2bf(acc[m][n][r]);
      }
}

// ---------------- fuse: h / x_esm from xW (bf16) ----------------
__global__ void k_fuse(const u16* __restrict__ xW, const int* __restrict__ nx,
                       const float* __restrict__ embp, const float* __restrict__ esm_b,
                       u16* __restrict__ feat){
  int t = blockIdx.x*256+threadIdx.x;
  if(t >= NN*64) return;
  int n = t>>6, c = (t&63)*8;
  uint4 q = *(const uint4*)(xW + (size_t)n*512 + c);
  int a = nx[n];
  float xw[8] = {blo(q.x),bhi(q.x),blo(q.y),bhi(q.y),blo(q.z),bhi(q.z),blo(q.w),bhi(q.w)};
  float h[8], ee[8];
  #pragma unroll
  for(int j=0;j<8;j++){
    float t1 = xw[j] + esm_b[c+j];
    float hh = embp[a*512 + c + j] + t1;
    h[j]  = hh>0.f?hh:0.f;
    ee[j] = t1>0.f?t1:0.f;
  }
  uint4 o1, o2;
  o1.x=pack2(h[0],h[1]); o1.y=pack2(h[2],h[3]); o1.z=pack2(h[4],h[5]); o1.w=pack2(h[6],h[7]);
  o2.x=pack2(ee[0],ee[1]); o2.y=pack2(ee[2],ee[3]); o2.z=pack2(ee[4],ee[5]); o2.w=pack2(ee[6],ee[7]);
  *(uint4*)(feat + (size_t)n*512 + c) = o1;
  *(uint4*)(feat + (size_t)(n+NN)*512 + c) = o2;
}

// ---------------- aggregation + finalize (one wave per dst node, both stacks) ----------------
__global__ __launch_bounds__(64) void k_agg(const u16* __restrict__ hW, u16* __restrict__ feat,
                 const int* __restrict__ offs, const int* __restrict__ csrs,
                 const float* __restrict__ csrw, const float* __restrict__ dis,
                 const float* __restrict__ bias, int layer){
  const int v = blockIdx.x;
  const int lane = threadIdx.x;
  const int nn  = (v < NN) ? v : v - NN;
  const int soff = (v < NN) ? 0 : NN;
  const int e0 = offs[nn], e1 = offs[nn+1];
  float acc[8] = {0,0,0,0,0,0,0,0};
  for(int e=e0;e<e1;++e){
    int s = csrs[e] + soff;
    float wgt = csrw[e];
    uint4 q = *(const uint4*)(hW + (size_t)s*512 + lane*8);
    acc[0]+=wgt*blo(q.x); acc[1]+=wgt*bhi(q.x);
    acc[2]+=wgt*blo(q.y); acc[3]+=wgt*bhi(q.y);
    acc[4]+=wgt*blo(q.z); acc[5]+=wgt*bhi(q.z);
    acc[6]+=wgt*blo(q.w); acc[7]+=wgt*bhi(q.w);
  }
  float dn = dis[nn]; float sn = dn*dn;
  uint4 qs = *(const uint4*)(hW + (size_t)v*512 + lane*8);
  acc[0]+=sn*blo(qs.x); acc[1]+=sn*bhi(qs.x); acc[2]+=sn*blo(qs.y); acc[3]+=sn*bhi(qs.y);
  acc[4]+=sn*blo(qs.z); acc[5]+=sn*bhi(qs.z); acc[6]+=sn*blo(qs.w); acc[7]+=sn*bhi(qs.w);
  float4 b0 = *(const float4*)(bias + lane*8);
  float4 b1 = *(const float4*)(bias + lane*8 + 4);
  acc[0]+=b0.x; acc[1]+=b0.y; acc[2]+=b0.z; acc[3]+=b0.w;
  acc[4]+=b1.x; acc[5]+=b1.y; acc[6]+=b1.z; acc[7]+=b1.w;
  #pragma unroll
  for(int j=0;j<8;j++) acc[j] = acc[j]>0.f ? acc[j] : 0.f;
  if(layer>0){
    uint4 qf = *(const uint4*)(feat + (size_t)v*512 + lane*8);
    acc[0]+=blo(qf.x); acc[1]+=bhi(qf.x); acc[2]+=blo(qf.y); acc[3]+=bhi(qf.y);
    acc[4]+=blo(qf.z); acc[5]+=bhi(qf.z); acc[6]+=blo(qf.w); acc[7]+=bhi(qf.w);
  }
  uint4 o;
  o.x=pack2(acc[0],acc[1]); o.y=pack2(acc[2],acc[3]);
  o.z=pack2(acc[4],acc[5]); o.w=pack2(acc[6],acc[7]);
  *(uint4*)(feat + (size_t)v*512 + lane*8) = o;
}

// ---------------- graph boundaries from sorted batch ----------------
__global__ void k_bounds(const int* __restrict__ batch, int* __restrict__ starts){
  int n = blockIdx.x*256+threadIdx.x;
  if(n>=NN) return;
  int b = batch[n];
  int pb = n ? batch[n-1] : -1;
  for(int g=pb+1; g<=b; g++) starts[g]=n;
  if(n==NN-1){ for(int g=b+1; g<=GG; g++) starts[g]=NN; }
}

// ---------------- partial max pool (values >= 0), u32-pair loads ----------------
__global__ void k_pool(const u16* __restrict__ feat, const int* __restrict__ starts,
                       u32* __restrict__ m1, u32* __restrict__ m3){
  int g = blockIdx.x, c = blockIdx.y;
  int s = starts[g], e = starts[g+1];
  int len = e - s;
  int b0 = s + (len*c)/8, b1 = s + (len*(c+1))/8;
  int t = threadIdx.x;
  float a0=0.f, a1=0.f, c0=0.f, c1=0.f;
  for(int n=b0;n<b1;++n){
    u32 q1 = *(const u32*)(feat + (size_t)n*512 + t*2);
    u32 q3 = *(const u32*)(feat + (size_t)(n+NN)*512 + t*2);
    a0 = fmaxf(a0, blo(q1)); a1 = fmaxf(a1, bhi(q1));
    c0 = fmaxf(c0, blo(q3)); c1 = fmaxf(c1, bhi(q3));
  }
  atomicMax(m1 + g*512 + t*2,     __float_as_uint(a0));
  atomicMax(m1 + g*512 + t*2 + 1, __float_as_uint(a1));
  atomicMax(m3 + g*512 + t*2,     __float_as_uint(c0));
  atomicMax(m3 + g*512 + t*2 + 1, __float_as_uint(c1));
}
__global__ void k_gcomb(const u32* __restrict__ m1, const u32* __restrict__ m3,
                        const float* __restrict__ w1, float* __restrict__ gc){
  int t = blockIdx.x*256+threadIdx.x; if(t>=GG*512) return;
  gc[t] = w1[0]*__uint_as_float(m1[t]) + w1[1]*__uint_as_float(m3[t]);
}

// ---------------- readout: wave-per-output dot products (transposed fp32 weights) ----------------
__global__ __launch_bounds__(256) void k_ro1v(const float* __restrict__ gc, const float* __restrict__ wT,
                                              const float* __restrict__ b, float* __restrict__ r1){
  int gw = blockIdx.x*4 + (threadIdx.x>>6);   // 0..65535  (g*1024+o)
  int g = gw >> 10, o = gw & 1023;
  int lane = threadIdx.x & 63;
  const float4* gr = (const float4*)(gc + (size_t)g*512);
  const float4* wr = (const float4*)(wT + (size_t)o*512);
  float s = 0.f;
  #pragma unroll
  for(int i=0;i<2;i++){
    float4 a = gr[i*64+lane];
    float4 w = wr[i*64+lane];
    s += a.x*w.x + a.y*w.y + a.z*w.z + a.w*w.w;
  }
  #pragma unroll
  for(int m=32;m>=1;m>>=1) s += __shfl_xor(s, m, 64);
  if(lane==0){ s += b[o]; r1[gw] = s>0.f ? s : 0.f; }
}
__global__ __launch_bounds__(256) void k_ro2v(const float* __restrict__ r1, const float* __restrict__ wT,
                                              const float* __restrict__ b, float* __restrict__ y){
  int gw = blockIdx.x*4 + (threadIdx.x>>6);   // 0..31999  (g*500+o)
  int g = gw/500, o = gw - g*500;
  int lane = threadIdx.x & 63;
  const float4* gr = (const float4*)(r1 + (size_t)g*1024);
  const float4* wr = (const float4*)(wT + (size_t)o*1024);
  float s = 0.f;
  #pragma unroll
  for(int i=0;i<4;i++){
    float4 a = gr[i*64+lane];
    float4 w = wr[i*64+lane];
    s += a.x*w.x + a.y*w.y + a.z*w.z + a.w*w.w;
  }
  #pragma unroll
  for(int m=32;m>=1;m>>=1) s += __shfl_xor(s, m, 64);
  if(lane==0) y[gw] = 1.0f/(1.0f+__expf(-(s + b[o])));
}

extern "C" void kernel_launch(void* const* d_in, const int* in_sizes, int n_in,
                              void* d_out, int out_size, void* d_ws, size_t ws_size,
                              hipStream_t stream){
  const int*   native_x = (const int*)d_in[0];
  const float* x        = (const float*)d_in[1];
  const int*   ei       = (const int*)d_in[2];
  const int*   batch    = (const int*)d_in[3];
  const float* embed_t  = (const float*)d_in[4];
  const float* paa_w    = (const float*)d_in[5];
  const float* paa_b    = (const float*)d_in[6];
  const float* pesm_w   = (const float*)d_in[7];
  const float* pesm_b   = (const float*)d_in[8];
  const float* gcn_w    = (const float*)d_in[9];
  const float* gcn_b    = (const float*)d_in[10];
  const float* ro1_w    = (const float*)d_in[11];
  const float* ro1_b    = (const float*)d_in[12];
  const float* ro2_w    = (const float*)d_in[13];
  const float* ro2_b    = (const float*)d_in[14];
  const float* w1       = (const float*)d_in[15];
  float* out = (float*)d_out;

  char* p = (char*)d_ws;
  auto alloc = [&](size_t n){ void* r = (void*)p; p += (n + 255) & ~(size_t)255; return r; };
  u16* feat   = (u16*)alloc((size_t)M2P*512*2);
  u16* hW     = (u16*)alloc((size_t)M2P*512*2);
  u16* xbf    = (u16*)alloc((size_t)M1P*1280*2);
  u16* WtE    = (u16*)alloc((size_t)512*1280*2);
  u16* WtG    = (u16*)alloc((size_t)3*512*512*2);
  float* roT1 = (float*)alloc((size_t)1024*512*4);
  float* roT2 = (float*)alloc((size_t)500*1024*4);
  float* embp = (float*)alloc(21*512*4);
  int* deg    = (int*)alloc(NN*4);
  float* dis  = (float*)alloc(NN*4);
  int* offs   = (int*)alloc((NN+1)*4);
  int* curs   = (int*)alloc(NN*4);
  int* csrs   = (int*)alloc(EE*4);
  float* csrw = (float*)alloc(EE*4);
  int* starts = (int*)alloc((GG+1)*4);
  u32* m1b    = (u32*)alloc(GG*512*4);
  u32* m3b    = (u32*)alloc(GG*512*4);
  float* gc   = (float*)alloc(GG*512*4);
  float* r1   = (float*)alloc(GG*1024*4);
  (void)ws_size; (void)in_sizes; (void)n_in; (void)out_size;

  hipMemsetAsync(deg,  0, NN*4, stream);
  hipMemsetAsync(curs, 0, NN*4, stream);
  hipMemsetAsync(m1b,  0, GG*512*4, stream);
  hipMemsetAsync(m3b,  0, GG*512*4, stream);

  k_cvt<<<(M1P*160+255)/256,256,0,stream>>>(x, xbf);
  k_transpose_cvt<<<dim3(16,40),dim3(32,32),0,stream>>>(pesm_w, WtE, 1280, 512);
  for(int i=0;i<3;i++)
    k_transpose_cvt<<<dim3(16,16),dim3(32,32),0,stream>>>(gcn_w+(size_t)i*262144, WtG+(size_t)i*262144, 512, 512);
  k_transpose_f32<<<dim3(32,16),dim3(32,32),0,stream>>>(ro1_w, roT1, 512, 1024);
  k_transpose_f32<<<dim3(16,32),dim3(32,32),0,stream>>>(ro2_w, roT2, 1024, 500);
  k_embp<<<42,256,0,stream>>>(embed_t, paa_w, paa_b, embp);
  k_deg<<<(EE+255)/256,256,0,stream>>>(ei, deg);
  k_dis<<<(NN+255)/256,256,0,stream>>>(deg, dis);
  k_scan<<<1,1024,0,stream>>>(deg, offs);
  k_fill<<<(EE+255)/256,256,0,stream>>>(ei, offs, curs, dis, csrs, csrw);

  // x @ proj_esm_w -> hW (bf16, rows stored 0..20000)
  k_gemm<<<dim3(4,157),256,0,stream>>>(xbf, WtE, hW, M1, 1280, 1280);
  k_fuse<<<(NN*64+255)/256,256,0,stream>>>(hW, native_x, embp, pesm_b, feat);

  for(int i=0;i<3;i++){
    k_gemm<<<dim3(4,313),256,0,stream>>>(feat, WtG+(size_t)i*262144, hW, M2, 512, 512);
    k_agg<<<M2,64,0,stream>>>(hW, feat, offs, csrs, csrw, dis, gcn_b+(size_t)i*512, i);
  }

  k_bounds<<<(NN+255)/256,256,0,stream>>>(batch, starts);
  k_pool<<<dim3(GG,8),256,0,stream>>>(feat, starts, m1b, m3b);
  k_gcomb<<<(GG*512+255)/256,256,0,stream>>>(m1b, m3b, w1, gc);
  k_ro1v<<<16384,256,0,stream>>>(gc, roT1, ro1_b, r1);
  k_ro2v<<<8000,256,0,stream>>>(r1, roT2, ro2_b, out);
}